// Round 13
// baseline (88.548 us; speedup 1.0000x reference)
//
#include <hip/hip_runtime.h>
#include <hip/hip_fp16.h>
#include <math.h>

// Problem constants (match reference exactly)
#define BROWS 1024
#define NPTS  32768
#define MPTS  16384          // complex FFT size via real-packing trick
#define NTHR  512            // 8 waves; 2 independent blocks co-resident per CU
#define MIN_IDX 1092         // argmin |f - 40/60|, f[k]=k*10/16384 (exact fp32 grid)
#define MAX_IDX 6827         // argmin |f - 250/60|
#define DENOMF  5732.0f      // MAX_IDX - MIN_IDX - 3

// Four-step FFT: 16384 = 128x128. n = 128*n1 + n2, k = k1 + 128*k2.
//   step1: Y[k1][n2] = sum_n1 F[k1][n1] Z[n1][n2]
//   twiddle: Bm = Y * W_16384^(k1*n2)
//   step3: X[k1+128*k2] = sum_n2 Bm[k1][n2] F[n2][k2]  (F symmetric)
// Wave w = panel p: k1/k2 rows 16p..16p+15, all 8 n0/m0 tiles.
// F matrix precomputed in d_ws (global, L1-hot). LDS: split real/imag
// planes, Zt -> Bm overlay -> Ct interleaved overlay (single buffer).
//
// LDS stride: LDH = 152 halfs = 76 words == 12 (mod 32). Frag-read bank
// quad = (3*r15 + g) mod 8 -> exactly 4 lanes/quad = 4-way (1.58x) vs the
// old 136-half stride's 8-way (2.94x). 16-B alignment preserved.

#define LDH 152              // halfs per plane row (304 B)
#define PLN (128 * LDH)      // halfs per plane (38912 B)

typedef _Float16 h8 __attribute__((ext_vector_type(8)));
typedef float    f4 __attribute__((ext_vector_type(4)));

#define MFMA(a, b, c) __builtin_amdgcn_mfma_f32_16x16x32_f16((a), (b), (c), 0, 0, 0)

#define ANG128 (-0.04908738521234052f)    // -2pi/128
#define ANG16K (-3.834951969714103e-4f)   // -2pi/16384
#define ANG32K (-1.9174759848570515e-4f)  // -2pi/32768

// MFMA fragment lane layout (gfx950 16x16x32, verified R8-R11 absmax=0):
//   A: lane l holds A[l&15][8*(l>>4)+j];  B: lane l holds B[8*(l>>4)+j][l&15]
//   D: lane l, reg v holds D[4*(l>>4)+v][l&15]

__device__ inline h8 ldf(const __half* p) {   // 16-B aligned b128 load
    return *reinterpret_cast<const h8*>(p);
}

// |X[k]|^2 (ortho) from interleaved Ct[k2][k1]; twiddle (c,sn) given.
__device__ inline float bin_pow(const __half2* __restrict__ C, int k,
                                float c, float sn) {
    float2 a  = __half22float2(C[(k >> 7) * LDH + (k & 127)]);
    int p = MPTS - k;
    float2 bz = __half22float2(C[(p >> 7) * LDH + (p & 127)]);
    float bx = bz.x, by = -bz.y;                  // conj(Z[M-k])
    float ex = 0.5f * (a.x + bx), ey = 0.5f * (a.y + by);
    float dx = a.x - bx,          dy = a.y - by;
    float ox = 0.5f * dy,         oy = -0.5f * dx;
    float Xx = ex + ox * c - oy * sn;
    float Xy = ey + ox * sn + oy * c;
    return (Xx * Xx + Xy * Xy) * (1.0f / (float)NPTS);
}

__device__ inline float bin_pow_sc(const __half2* __restrict__ C, int k) {
    float c, sn;
    __sincosf(ANG32K * (float)k, &sn, &c);
    return bin_pow(C, k, c, sn);
}

// F table: Fr plane [128][128] halfs, then Fi plane. 64 KiB in d_ws.
__global__ __launch_bounds__(256) void finit_kernel(__half* __restrict__ Ft) {
    int i = blockIdx.x * 256 + threadIdx.x;     // 16384 entries
    int r = i >> 7, c = i & 127;
    float s, co;
    __sincosf(ANG128 * (float)((r * c) & 127), &s, &co);
    Ft[i]         = (__half)co;
    Ft[16384 + i] = (__half)s;
}

// (512, 4): VGPR cap 64. Residency law (R5/R6/R9/R11): ~256 VGPR/SIMD pool,
// so 2 blocks x 8 waves = 4 waves/SIMD needs VGPR <= 64 (R9 landed exactly
// 64 with this shape). LDS 77.8 KB x 2 = 155.6 KB <= 160 -> 2 blocks/CU.
// Spill tripwires: WRITE_SIZE >> 32 KB, FETCH_SIZE >> 67 MB.
__global__ __launch_bounds__(NTHR, 4) void snr_row_kernel(
        const float* __restrict__ outs,
        const float* __restrict__ targets,
        const __half* __restrict__ Ft,
        float* __restrict__ row_loss) {
    __shared__ __align__(16) __half pl[2 * PLN];  // 76 KiB (2 planes)
    __shared__ float red[NTHR / 64];

    const int b    = blockIdx.x;
    const int tid  = threadIdx.x;
    const int lane = tid & 63;
    const int p    = tid >> 6;          // wave id 0..7 = panel id
    const int r15  = lane & 15;
    const int g    = lane >> 4;         // 0..3
    const float2* row = reinterpret_cast<const float2*>(outs + (size_t)b * NPTS);

    // ---- Stage: Zt[n2][n1], split planes (coalesced global b64 reads)
    #pragma unroll
    for (int it = 0; it < MPTS / NTHR; ++it) {
        int m = tid + it * NTHR;
        float2 v = row[m];
        int idx = (m & 127) * LDH + (m >> 7);
        pl[idx]       = (__half)v.x;
        pl[PLN + idx] = (__half)v.y;
    }
    __syncthreads();

    // F fragment row base for panel p (serves both steps; L1-hot).
    const __half* FrB = Ft + (16 * p + r15) * 128;
    const __half* FiB = Ft + 16384 + (16 * p + r15) * 128;

    // ---- Step 1: Y(panel p) = F * Z; twiddle; pack panel into registers.
    __half2 bm[8][4];                   // 32 VGPR, statically indexed
    #pragma unroll
    for (int n0 = 0; n0 < 8; ++n0) {
        f4 accr = {0.f, 0.f, 0.f, 0.f}, acci = {0.f, 0.f, 0.f, 0.f};
        #pragma unroll
        for (int kc = 0; kc < 4; ++kc) {
            int base = (16 * n0 + r15) * LDH + 32 * kc + 8 * g;
            h8 zr = ldf(&pl[base]);
            h8 zi = ldf(&pl[PLN + base]);
            h8 fr = ldf(&FrB[32 * kc + 8 * g]);
            h8 fi = ldf(&FiB[32 * kc + 8 * g]);
            h8 fin = -fi;
            accr = MFMA(fr,  zr, accr);     // Yr = Fr Zr - Fi Zi
            accr = MFMA(fin, zi, accr);
            acci = MFMA(fr,  zi, acci);     // Yi = Fr Zi + Fi Zr
            acci = MFMA(fi,  zr, acci);
        }
        #pragma unroll
        for (int v = 0; v < 4; ++v) {
            int k1 = 16 * p + 4 * g + v;
            int n2 = 16 * n0 + r15;
            int e  = (k1 * n2) & 16383;
            float s, c;
            __sincosf(ANG16K * (float)e, &s, &c);
            bm[n0][v] = __floats2half2_rn(accr[v] * c - acci[v] * s,
                                          accr[v] * s + acci[v] * c);
        }
    }
    __syncthreads();    // all Zt reads complete

    // ---- Overlay-write Bm[k1][n2] into split planes (wave-owned rows)
    #pragma unroll
    for (int n0 = 0; n0 < 8; ++n0)
        #pragma unroll
        for (int v = 0; v < 4; ++v) {
            int idx = (16 * p + 4 * g + v) * LDH + 16 * n0 + r15;
            pl[idx]       = __low2half(bm[n0][v]);
            pl[PLN + idx] = __high2half(bm[n0][v]);
        }
    __syncthreads();

    // ---- Step 3: X = Bm * F (col panel p); pack panel into registers.
    __half2 ct[8][4];                   // reuses bm's registers (bm dead)
    #pragma unroll
    for (int m0 = 0; m0 < 8; ++m0) {
        f4 accr = {0.f, 0.f, 0.f, 0.f}, acci = {0.f, 0.f, 0.f, 0.f};
        #pragma unroll
        for (int kc = 0; kc < 4; ++kc) {
            int base = (16 * m0 + r15) * LDH + 32 * kc + 8 * g;
            h8 ar = ldf(&pl[base]);
            h8 ai = ldf(&pl[PLN + base]);
            h8 fr = ldf(&FrB[32 * kc + 8 * g]);
            h8 fi = ldf(&FiB[32 * kc + 8 * g]);
            h8 ain = -ai;
            accr = MFMA(ar,  fr, accr);     // Xr = Br Fr - Bi Fi
            accr = MFMA(ain, fi, accr);
            acci = MFMA(ar,  fi, acci);     // Xi = Br Fi + Bi Fr
            acci = MFMA(ai,  fr, acci);
        }
        #pragma unroll
        for (int v = 0; v < 4; ++v)
            ct[m0][v] = __floats2half2_rn(accr[v], acci[v]);
    }
    __syncthreads();    // all Bm reads complete

    // ---- Overlay-write interleaved Ct[k2][k1] across both planes
    // (128 * LDH half2 == exactly the 2 planes of halfs).
    __half2* C = reinterpret_cast<__half2*>(pl);
    #pragma unroll
    for (int m0 = 0; m0 < 8; ++m0)
        #pragma unroll
        for (int v = 0; v < 4; ++v)
            C[(16 * p + r15) * LDH + 16 * m0 + 4 * g + v] = ct[m0][v];
    __syncthreads();

    // ---- Band power sum [MIN_IDX, MAX_IDX): direct indexing, coalesced.
    float local = 0.0f;
    for (int k = MIN_IDX + tid; k < MAX_IDX; k += NTHR)
        local += bin_pow_sc(C, k);

    for (int off = 32; off; off >>= 1) local += __shfl_down(local, off);
    if (lane == 0) red[p] = local;
    __syncthreads();

    if (tid == 0) {
        float S = 0.0f;
        #pragma unroll
        for (int q = 0; q < NTHR / 64; ++q) S += red[q];

        // ref_idx: argmin_k |f[k]-t|, f[k] = k*(10/16384) exact in fp32.
        float tgt = targets[b];
        double kd = (double)tgt * (16384.0 / 10.0);
        int k0 = (int)kd;                       // t>0 so trunc == floor
        const float stepf = 10.0f / 16384.0f;   // exactly representable
        float f0 = (float)k0 * stepf;           // exact products (<=24b)
        float f1 = (float)(k0 + 1) * stepf;
        float d0 = fabsf(f0 - tgt);
        float d1 = fabsf(f1 - tgt);
        int rr = (d0 <= d1) ? k0 : (k0 + 1);

        float pm1 = bin_pow_sc(C, rr - 1);
        float p0  = bin_pow_sc(C, rr);
        float pp1 = bin_pow_sc(C, rr + 1);
        float other_avg = (S - pm1 - p0 - pp1) * (1.0f / DENOMF);
        row_loss[b] = -10.0f * log10f(p0 / other_avg);
    }
}

__global__ __launch_bounds__(256) void snr_reduce_kernel(
        const float* __restrict__ row_loss, float* __restrict__ out) {
    __shared__ float red[4];
    float s = 0.0f;
    for (int i = threadIdx.x; i < BROWS; i += 256) s += row_loss[i];
    for (int off = 32; off; off >>= 1) s += __shfl_down(s, off);
    if ((threadIdx.x & 63) == 0) red[threadIdx.x >> 6] = s;
    __syncthreads();
    if (threadIdx.x == 0)
        out[0] = (red[0] + red[1] + red[2] + red[3]) * (1.0f / (float)BROWS);
}

extern "C" void kernel_launch(void* const* d_in, const int* in_sizes, int n_in,
                              void* d_out, int out_size, void* d_ws, size_t ws_size,
                              hipStream_t stream) {
    const float* outs    = (const float*)d_in[0];
    const float* targets = (const float*)d_in[1];
    float*  ws_loss = (float*)d_ws;                             // 4 KiB
    __half* Ft      = (__half*)((char*)d_ws + 4096);            // 64 KiB table
    float* out = (float*)d_out;

    finit_kernel<<<64, 256, 0, stream>>>(Ft);
    snr_row_kernel<<<BROWS, NTHR, 0, stream>>>(outs, targets, Ft, ws_loss);
    snr_reduce_kernel<<<1, 256, 0, stream>>>(ws_loss, out);
}

// Round 14
// 60.537 us; speedup vs baseline: 1.4627x; 1.4627x over previous
//
#include <hip/hip_runtime.h>
#include <hip/hip_fp16.h>
#include <math.h>

// Problem constants (match reference exactly)
#define BROWS 1024
#define NPTS  32768
#define MPTS  16384          // complex FFT size via real-packing trick
#define NTHR  512            // 8 waves; 2 independent blocks co-resident per CU
#define MIN_IDX 1092         // argmin |f - 40/60|, f[k]=k*10/16384 (exact fp32 grid)
#define MAX_IDX 6827         // argmin |f - 250/60|
#define DENOMF  5732.0f      // MAX_IDX - MIN_IDX - 3

// Four-step FFT: 16384 = 128x128. n = 128*n1 + n2, k = k1 + 128*k2.
//   step1: Y[k1][n2] = sum_n1 F[k1][n1] Z[n1][n2]   (F = 128-pt DFT matrix)
//   twiddle: Bm = Y * W_16384^(k1*n2)
//   step3: X[k1+128*k2] = sum_n2 Bm[k1][n2] F[n2][k2]   (F symmetric)
// R9 structure (measured best, 60.4 us): F fragments computed once per wave
// into registers (no table -> no L1 thrash); Bm panel held in registers
// across the barrier (single LDS buffer); interleaved half2 storage.
// LD = 132 (was 140): 528-B rows, 16-B aligned; frag-read quad =
// (r + 2g) mod 8 -> uniform 8 lanes/quad = b128 floor; saves 2 KB LDS.

#define LD 132   // LDS row stride in half2 words

typedef _Float16 h8 __attribute__((ext_vector_type(8)));
typedef float    f4 __attribute__((ext_vector_type(4)));

#define MFMA(a, b, c) __builtin_amdgcn_mfma_f32_16x16x32_f16((a), (b), (c), 0, 0, 0)

#define ANG128 (-0.04908738521234052f)    // -2pi/128
#define ANG16K (-3.834951969714103e-4f)   // -2pi/16384
#define ANG32K (-1.9174759848570515e-4f)  // -2pi/32768

// MFMA fragment lane layout (gfx950 16x16x32, verified R8-R12 absmax=0):
//   A: lane l holds A[l&15][8*(l>>4)+j];  B: lane l holds B[8*(l>>4)+j][l&15]
//   D: lane l, reg v holds D[4*(l>>4)+v][l&15]

struct Frag { h8 r, i; };

// Load a complex fragment from an LDS half2 matrix: 8 consecutive half2
// (two ds_read_b128), de-interleave into real/imag h8 vectors.
__device__ inline Frag load_frag(const __half2* __restrict__ base) {
    const float4* p = reinterpret_cast<const float4*>(base);
    union { float4 f; _Float16 h[8]; } a, b;
    a.f = p[0]; b.f = p[1];
    Frag fr;
    fr.r = (h8){a.h[0], a.h[2], a.h[4], a.h[6], b.h[0], b.h[2], b.h[4], b.h[6]};
    fr.i = (h8){a.h[1], a.h[3], a.h[5], a.h[7], b.h[1], b.h[3], b.h[5], b.h[7]};
    return fr;
}

// F-matrix fragment on the fly: F[row][k] = e^{-2pi i (row*k)/128}, k = kbase+j.
// Integer reduction (row*k)&127 keeps __sincosf args in [-2pi, 0].
__device__ inline void make_F(int row, int kbase, h8& fr, h8& fi) {
    #pragma unroll
    for (int j = 0; j < 8; ++j) {
        int e = (row * (kbase + j)) & 127;
        float ang = ANG128 * (float)e;
        float s, c;
        __sincosf(ang, &s, &c);
        fr[j] = (_Float16)c;
        fi[j] = (_Float16)s;
    }
}

// |X[k]|^2 (ortho) from the complex-FFT matrix C[k2][k1] (direct indexing).
__device__ inline float bin_pow(const __half2* __restrict__ C, int k) {
    float2 a  = __half22float2(C[(k >> 7) * LD + (k & 127)]);
    int p = MPTS - k;
    float2 bz = __half22float2(C[(p >> 7) * LD + (p & 127)]);
    float bx = bz.x, by = -bz.y;                  // conj(Z[M-k])
    float ex = 0.5f * (a.x + bx), ey = 0.5f * (a.y + by);   // Xe[k]
    float dx = a.x - bx,          dy = a.y - by;
    float ox = 0.5f * dy,         oy = -0.5f * dx;          // Xo[k]
    float ang = ANG32K * (float)k;
    float c, sn;
    __sincosf(ang, &sn, &c);
    float Xx = ex + ox * c - oy * sn;
    float Xy = ey + ox * sn + oy * c;
    return (Xx * Xx + Xy * Xy) * (1.0f / (float)NPTS);      // ortho: |X|^2 / N
}

// (512, 4): VGPR target 64 (proven: R9 landed exactly 64, no spill, and the
// HW packs two 8-wave blocks/CU). Spill tripwires: WRITE_SIZE >> 32 KB,
// FETCH_SIZE >> 66 MB. Do NOT add register state (R10: +16 recurrence regs
// -> 14 MB scratch traffic) and do NOT use a global F table (R12: L1 thrash,
// FETCH +31 MB).
__global__ __launch_bounds__(NTHR, 4) void snr_row_kernel(
        const float* __restrict__ outs,
        const float* __restrict__ targets,
        float* __restrict__ row_loss) {
    __shared__ __align__(16) __half2 bufA[128 * LD];    // 66 KiB single buffer
    __shared__ float red[NTHR / 64];

    const int b    = blockIdx.x;
    const int tid  = threadIdx.x;
    const int lane = tid & 63;
    const int w    = tid >> 6;          // wave id 0..7 = panel id
    const int r15  = lane & 15;
    const int g    = lane >> 4;         // 0..3
    const float2* row = reinterpret_cast<const float2*>(outs + (size_t)b * NPTS);

    // ---- Stage: Zt[n2][n1] = z[128*n1 + n2] transposed (coalesced global)
    #pragma unroll
    for (int it = 0; it < MPTS / NTHR; ++it) {
        int m = tid + it * NTHR;
        float2 v = row[m];
        bufA[(m & 127) * LD + (m >> 7)] = __floats2half2_rn(v.x, v.y);
    }

    // ---- F fragments for this wave's panel: F[16w+r15][32kc+8g+j].
    // Serve step1 A-side (row=k1) and step3 B-side (col=k2, F symmetric).
    h8 fr[4], fi[4];
    #pragma unroll
    for (int kc = 0; kc < 4; ++kc)
        make_F(16 * w + r15, 32 * kc + 8 * g, fr[kc], fi[kc]);
    __syncthreads();

    // ---- Step 1: Y(panel w) = F * Z; twiddle; PACK PANEL INTO REGISTERS.
    __half2 bm[8][4];                   // 32 VGPR, statically indexed
    #pragma unroll
    for (int n0 = 0; n0 < 8; ++n0) {
        f4 accr = {0.f, 0.f, 0.f, 0.f}, acci = {0.f, 0.f, 0.f, 0.f};
        #pragma unroll
        for (int kc = 0; kc < 4; ++kc) {
            Frag z = load_frag(&bufA[(16 * n0 + r15) * LD + 32 * kc + 8 * g]);
            h8 fin = -fi[kc];
            accr = MFMA(fr[kc], z.r, accr);     // Yr = Fr Zr - Fi Zi
            accr = MFMA(fin,    z.i, accr);
            acci = MFMA(fr[kc], z.i, acci);     // Yi = Fr Zi + Fi Zr
            acci = MFMA(fi[kc], z.r, acci);
        }
        #pragma unroll
        for (int v = 0; v < 4; ++v) {
            int k1 = 16 * w + 4 * g + v;
            int n2 = 16 * n0 + r15;
            int e  = (k1 * n2) & 16383;
            float s, c;
            __sincosf(ANG16K * (float)e, &s, &c);
            bm[n0][v] = __floats2half2_rn(accr[v] * c - acci[v] * s,
                                          accr[v] * s + acci[v] * c);
        }
    }
    __syncthreads();    // all Zt reads complete

    // ---- Overlay-write Bm[k1][n2] (wave w owns rows 16w..16w+15)
    #pragma unroll
    for (int n0 = 0; n0 < 8; ++n0)
        #pragma unroll
        for (int v = 0; v < 4; ++v)
            bufA[(16 * w + 4 * g + v) * LD + 16 * n0 + r15] = bm[n0][v];
    __syncthreads();

    // ---- Step 3: X = Bm * F (col panel w); pack panel into registers.
    __half2 ct[8][4];                   // reuses bm's registers (bm dead)
    #pragma unroll
    for (int m0 = 0; m0 < 8; ++m0) {
        f4 accr = {0.f, 0.f, 0.f, 0.f}, acci = {0.f, 0.f, 0.f, 0.f};
        #pragma unroll
        for (int kc = 0; kc < 4; ++kc) {
            Frag a = load_frag(&bufA[(16 * m0 + r15) * LD + 32 * kc + 8 * g]);
            h8 ain = -a.i;
            accr = MFMA(a.r, fr[kc], accr);     // Xr = Br Fr - Bi Fi
            accr = MFMA(ain, fi[kc], accr);
            acci = MFMA(a.r, fi[kc], acci);     // Xi = Br Fi + Bi Fr
            acci = MFMA(a.i, fr[kc], acci);
        }
        #pragma unroll
        for (int v = 0; v < 4; ++v)
            ct[m0][v] = __floats2half2_rn(accr[v], acci[v]);
    }
    __syncthreads();    // all Bm reads complete

    // ---- Overlay-write Ct[k2][k1] (wave w owns rows k2 = 16w..16w+15)
    #pragma unroll
    for (int m0 = 0; m0 < 8; ++m0)
        #pragma unroll
        for (int v = 0; v < 4; ++v)
            bufA[(16 * w + r15) * LD + 16 * m0 + 4 * g + v] = ct[m0][v];
    __syncthreads();

    // ---- Band power sum [MIN_IDX, MAX_IDX): direct k indexing, coalesced.
    float local = 0.0f;
    for (int k = MIN_IDX + tid; k < MAX_IDX; k += NTHR)
        local += bin_pow(bufA, k);

    for (int off = 32; off; off >>= 1) local += __shfl_down(local, off);
    if (lane == 0) red[w] = local;
    __syncthreads();

    if (tid == 0) {
        float S = 0.0f;
        #pragma unroll
        for (int q = 0; q < NTHR / 64; ++q) S += red[q];

        // ref_idx: argmin_k |f[k]-t|, f[k] = k*(10/16384) exact in fp32.
        float tgt = targets[b];
        double kd = (double)tgt * (16384.0 / 10.0);
        int k0 = (int)kd;                       // t>0 so trunc == floor
        const float stepf = 10.0f / 16384.0f;   // exactly representable
        float f0 = (float)k0 * stepf;           // exact products (<=24b)
        float f1 = (float)(k0 + 1) * stepf;
        float d0 = fabsf(f0 - tgt);
        float d1 = fabsf(f1 - tgt);
        int rr = (d0 <= d1) ? k0 : (k0 + 1);

        float pm1 = bin_pow(bufA, rr - 1);
        float p0  = bin_pow(bufA, rr);
        float pp1 = bin_pow(bufA, rr + 1);
        float other_avg = (S - pm1 - p0 - pp1) * (1.0f / DENOMF);
        row_loss[b] = -10.0f * log10f(p0 / other_avg);
    }
}

__global__ __launch_bounds__(256) void snr_reduce_kernel(
        const float* __restrict__ row_loss, float* __restrict__ out) {
    __shared__ float red[4];
    float s = 0.0f;
    for (int i = threadIdx.x; i < BROWS; i += 256) s += row_loss[i];
    for (int off = 32; off; off >>= 1) s += __shfl_down(s, off);
    if ((threadIdx.x & 63) == 0) red[threadIdx.x >> 6] = s;
    __syncthreads();
    if (threadIdx.x == 0)
        out[0] = (red[0] + red[1] + red[2] + red[3]) * (1.0f / (float)BROWS);
}

extern "C" void kernel_launch(void* const* d_in, const int* in_sizes, int n_in,
                              void* d_out, int out_size, void* d_ws, size_t ws_size,
                              hipStream_t stream) {
    const float* outs    = (const float*)d_in[0];
    const float* targets = (const float*)d_in[1];
    float* ws  = (float*)d_ws;    // 1024 per-row losses
    float* out = (float*)d_out;

    snr_row_kernel<<<BROWS, NTHR, 0, stream>>>(outs, targets, ws);
    snr_reduce_kernel<<<1, 256, 0, stream>>>(ws, out);
}